// Round 16
// baseline (75.575 us; speedup 1.0000x reference)
//
#include <hip/hip_runtime.h>
#include <hip/hip_bf16.h>

namespace {

constexpr int kB = 16;
constexpr int kSEQ = 100;
constexpr int kNS = 101;
constexpr int kD = 128;
constexpr int kH = 8;

typedef __attribute__((ext_vector_type(8))) __bf16 bf16x8;
typedef __attribute__((ext_vector_type(4))) float f32x4;

__device__ __forceinline__ unsigned short f2bf(float f) {
  union { float f; unsigned int u; } c;
  c.f = f;
  unsigned int u = c.u;
  u += 0x7FFFu + ((u >> 16) & 1u);
  return (unsigned short)(u >> 16);
}

__device__ __forceinline__ float leaky(float x) {
  return x > 0.f ? x : 0.01f * x;
}

__device__ __forceinline__ float logit_bias(float p) {
  p = fminf(fmaxf(p, 1e-6f), 1.f - 1e-6f);
  return __logf(__fdividef(p, 1.f - p));
}

__device__ __forceinline__ bf16x8 pack8(const float* y) {
  bf16x8 r;
  r[0] = (__bf16)y[0]; r[1] = (__bf16)y[1];
  r[2] = (__bf16)y[2]; r[3] = (__bf16)y[3];
  r[4] = (__bf16)y[4]; r[5] = (__bf16)y[5];
  r[6] = (__bf16)y[6]; r[7] = (__bf16)y[7];
  return r;
}

// ---------------------------------------------------------------------------
// K_FRONT: fused {qkv-proj | U/Q-proj+stats | W2->bf16}. grid 480, 256 thr.
// ---------------------------------------------------------------------------
__global__ __launch_bounds__(256) void k_front(
    const float* __restrict__ nve,
    const float* __restrict__ Wq, const float* __restrict__ bq,
    const float* __restrict__ Wk, const float* __restrict__ bk,
    const float* __restrict__ Wv, const float* __restrict__ bv,
    const float* __restrict__ Wa,
    const float* __restrict__ desc, const float* __restrict__ W1,
    const float* __restrict__ b1, const float* __restrict__ W2,
    float* __restrict__ v, float* __restrict__ sq, float* __restrict__ sk,
    float* __restrict__ U, float* __restrict__ Qm,
    float* __restrict__ su_, float* __restrict__ nu_,
    float* __restrict__ sw_, float* __restrict__ nw_,
    unsigned short* __restrict__ W2bf) {
  __shared__ float X[8][128];
  __shared__ float part[4][4][4];
  const int bid = blockIdx.x;
  const int tid = threadIdx.x;

  if (bid < 208) {
    const int b = bid / 13;
    const int n0 = (bid % 13) * 8;
    const int d = tid & 127, rh = tid >> 7;
    {
      int r = tid >> 5, c = (tid & 31) * 4;
      int n = n0 + r; if (n > 100) n = 100;
      *(float4*)&X[r][c] = *(const float4*)&nve[((size_t)(b * kNS + n)) * kD + c];
    }
    __syncthreads();

    float aq[4], ak[4], av[4];
    const float bqv = bq[d], bkv = bk[d], bvv = bv[d];
    #pragma unroll
    for (int r = 0; r < 4; ++r) { aq[r] = bqv; ak[r] = bkv; av[r] = bvv; }

    const float* wqr = Wq + (size_t)d * kD;
    const float* wkr = Wk + (size_t)d * kD;
    const float* wvr = Wv + (size_t)d * kD;
    for (int kk = 0; kk < kD; ++kk) {
      float wq = wqr[kk], wk = wkr[kk], wv = wvr[kk];
      #pragma unroll
      for (int r = 0; r < 4; ++r) {
        float x = X[rh * 4 + r][kk];
        aq[r] += wq * x;
        ak[r] += wk * x;
        av[r] += wv * x;
      }
    }

    const int t = d & 15, h = d >> 4;
    const float waq = Wa[t], wak = Wa[16 + t];
    #pragma unroll
    for (int r = 0; r < 4; ++r) {
      int n = n0 + rh * 4 + r;
      if (n < kNS) {
        v[((size_t)(b * kNS + n)) * kD + d] = av[r];
        float cq = leaky(aq[r]) * waq;
        float ck = leaky(ak[r]) * wak;
        cq += __shfl_xor(cq, 1); ck += __shfl_xor(ck, 1);
        cq += __shfl_xor(cq, 2); ck += __shfl_xor(ck, 2);
        cq += __shfl_xor(cq, 4); ck += __shfl_xor(ck, 4);
        cq += __shfl_xor(cq, 8); ck += __shfl_xor(ck, 8);
        if (t == 0) {
          sq[(b * kH + h) * kNS + n] = cq;
          sk[(b * kH + h) * kNS + n] = ck;
        }
      }
    }
  } else if (bid < 416) {
    const int id = bid - 208;
    const int b = id / 13;
    const int s0 = (id % 13) * 8;
    const int d = tid & 127, rh = tid >> 7;
    const int lane = tid & 63, wv = tid >> 6;
    {
      int r = tid >> 5, c = (tid & 31) * 4;
      int s = s0 + r; if (s > 99) s = 99;
      *(float4*)&X[r][c] = *(const float4*)&desc[((size_t)(b * kSEQ + s)) * kD + c];
    }
    __syncthreads();

    float aU[4], aQ[4];
    const float b1v = b1[d];
    #pragma unroll
    for (int r = 0; r < 4; ++r) { aU[r] = b1v; aQ[r] = 0.f; }

    const float* w1r = W1 + (size_t)d * (2 * kD);
    for (int kk = 0; kk < kD; ++kk) {
      float wa = w1r[kk], wb = w1r[kD + kk];
      #pragma unroll
      for (int r = 0; r < 4; ++r) {
        float x = X[rh * 4 + r][kk];
        aU[r] += wa * x;
        aQ[r] += wb * x;
      }
    }
    #pragma unroll
    for (int r = 0; r < 4; ++r) {
      int s = s0 + rh * 4 + r;
      if (s < kSEQ) {
        size_t base = ((size_t)(b * kSEQ + s)) * kD + d;
        U[base] = aU[r];
        Qm[base] = aQ[r];
      }
    }
    #pragma unroll
    for (int r = 0; r < 4; ++r) {
      float s1 = aU[r], s2 = aU[r] * aU[r], s3 = aQ[r], s4 = aQ[r] * aQ[r];
      #pragma unroll
      for (int m = 1; m < 64; m <<= 1) {
        s1 += __shfl_xor(s1, m);
        s2 += __shfl_xor(s2, m);
        s3 += __shfl_xor(s3, m);
        s4 += __shfl_xor(s4, m);
      }
      if (lane == 0) {
        part[wv][r][0] = s1; part[wv][r][1] = s2;
        part[wv][r][2] = s3; part[wv][r][3] = s4;
      }
    }
    __syncthreads();
    if (tid < 32) {
      int r = tid & 7, st = tid >> 3;
      int rh2 = r >> 2, rl = r & 3;
      float val = part[rh2 * 2][rl][st] + part[rh2 * 2 + 1][rl][st];
      int s = s0 + r;
      if (s < kSEQ) {
        float* dst = (st == 0) ? su_ : (st == 1) ? nu_ : (st == 2) ? sw_ : nw_;
        dst[b * kSEQ + s] = val;
      }
    }
  } else {
    int idx = (bid - 416) * 256 + tid;
    W2bf[idx] = f2bf(W2[idx]);
  }
}

// ---------------------------------------------------------------------------
// K_MID: fused {SE transposed-GEMM | CLS row}, writing FINAL LOGITS
// (sq + sk + SE + ba + maskM-bias) into the attn region.
// grid 1712, 512 thr (8 waves): SE blocks 1 i-row, wave w owns j-tile w;
// CLS blocks wave w owns n-tile w.
// ---------------------------------------------------------------------------
__global__ __launch_bounds__(512) void k_mid(
    const float* __restrict__ U, const float* __restrict__ Qm,
    const float* __restrict__ su_, const float* __restrict__ nu_,
    const float* __restrict__ sw_, const float* __restrict__ nw_,
    const unsigned short* __restrict__ W2bf,
    const float* __restrict__ lng, const float* __restrict__ lnb,
    const float* __restrict__ b2, const float* __restrict__ Wa,
    const float* __restrict__ sq, const float* __restrict__ sk,
    const float* __restrict__ maskM, const float* __restrict__ ba,
    float* __restrict__ LG) {
  const int bid = blockIdx.x;
  const int tid = threadIdx.x;
  const int lane = tid & 63, w = tid >> 6;
  const int lr = lane & 15, lg = lane >> 4;

  __shared__ __align__(16) unsigned short W2sh[128 * 128];  // 32 KB swizzled
  __shared__ __align__(16) float gsh[128], bsh[128], b2sh[128];
  __shared__ float SEsh0[16][8];

  #pragma unroll
  for (int itr = 0; itr < 4; ++itr) {
    uint4 val = ((const uint4*)W2bf)[itr * 512 + tid];
    int f = (itr * 512 + tid) * 8;
    int row = f >> 7, g8 = (f >> 3) & 15;
    *(uint4*)&W2sh[row * 128 + ((g8 ^ (row & 15)) << 3)] = val;
  }
  if (tid < 128) {
    gsh[tid] = lng[tid];
    b2sh[tid] = b2[tid];
  } else if (tid < 256) {
    bsh[tid - 128] = lnb[tid - 128];
  }

  if (bid < 1600) {
    // ---------------- SE row i0, 8-way j; write final logits ----------------
    const int i0 = bid % 100;
    const int b = bid / 100;
    const int i = i0 + 1;

    const float* Urow = U + ((size_t)(b * kSEQ + i0)) * kD;
    float Ureg[32];
    #pragma unroll
    for (int ks = 0; ks < 4; ++ks) {
      int off = ks * 32 + lg * 8;
      *(float4*)&Ureg[ks * 8] = *(const float4*)&Urow[off];
      *(float4*)&Ureg[ks * 8 + 4] = *(const float4*)&Urow[off + 4];
    }
    const float suv = su_[b * kSEQ + i0], nuv = nu_[b * kSEQ + i0];
    float wa4[4];
    *(float4*)wa4 = *(const float4*)&Wa[32 + 4 * lg];
    const float bav = ba[0];

    const int j1 = w * 16 + lr;          // wave w owns j-tile w (0..7)
    const int j1c = j1 > 99 ? 99 : j1;
    const float swv = sw_[b * kSEQ + j1c];
    const float nwv = nw_[b * kSEQ + j1c];
    const float* Qrow = Qm + ((size_t)(b * kSEQ + j1c)) * kD;
    float Qreg[32];
    #pragma unroll
    for (int ks = 0; ks < 4; ++ks) {
      const int off = ks * 32 + lg * 8;
      *(float4*)&Qreg[ks * 8] = *(const float4*)&Qrow[off];
      *(float4*)&Qreg[ks * 8 + 4] = *(const float4*)&Qrow[off + 4];
    }
    float gpart = 0.f;
    #pragma unroll
    for (int e = 0; e < 32; ++e) gpart = __builtin_fmaf(Ureg[e], Qreg[e], gpart);
    gpart += __shfl_xor(gpart, 16);
    gpart += __shfl_xor(gpart, 32);

    const float mean = (suv + swv) * (1.f / 128.f);
    const float ex2 = (nuv + nwv + 2.f * gpart) * (1.f / 128.f);
    const float var = ex2 - mean * mean;
    const float rstd = rsqrtf(var + 1e-5f);
    const float amul = rstd, aadd = -mean * rstd;
    __syncthreads();

    bf16x8 Bf[4];
    #pragma unroll
    for (int ks = 0; ks < 4; ++ks) {
      const int off = ks * 32 + lg * 8;
      float gg[8], bb[8], ys[8];
      *(float4*)&gg[0] = *(const float4*)&gsh[off];
      *(float4*)&gg[4] = *(const float4*)&gsh[off + 4];
      *(float4*)&bb[0] = *(const float4*)&bsh[off];
      *(float4*)&bb[4] = *(const float4*)&bsh[off + 4];
      #pragma unroll
      for (int ee = 0; ee < 8; ++ee) {
        float x = Ureg[ks * 8 + ee] + Qreg[ks * 8 + ee];
        float tt = __builtin_fmaf(x, amul, aadd);
        ys[ee] = fmaxf(__builtin_fmaf(tt, gg[ee], bb[ee]), 0.f);
      }
      Bf[ks] = pack8(ys);
    }

    // per-lane logit extras (lanes 0-15 are the storing lanes)
    const int hbase = b * kH;
    const float skv = sk[(size_t)hbase * kNS + j1 + 1];  // head-invariant part? no:
    // sk depends on h; load per-h below instead.
    (void)skv;
    #pragma unroll
    for (int h = 0; h < 8; ++h) {
      f32x4 acc = *(const f32x4*)&b2sh[h * 16 + 4 * lg];  // C-init = b2
      #pragma unroll
      for (int ks = 0; ks < 4; ++ks) {
        const int row = h * 16 + lr;
        const int g8 = (ks * 4 + lg) ^ lr;
        bf16x8 Af = *(const bf16x8*)&W2sh[row * 128 + g8 * 8];
        acc = __builtin_amdgcn_mfma_f32_16x16x32_bf16(Af, Bf[ks], acc, 0, 0, 0);
      }
      float s = 0.f;
      #pragma unroll
      for (int r = 0; r < 4; ++r) s += leaky(acc[r]) * wa4[r];
      s += __shfl_xor(s, 16);
      s += __shfl_xor(s, 32);
      if (lane < 16 && j1 <= 99) {
        const int skbase = (hbase + h) * kNS;
        float lgt = s + sq[skbase + i] + sk[skbase + j1 + 1] + bav;
        lgt += logit_bias(maskM[(((size_t)(hbase + h)) * kSEQ + i0) * kSEQ + j1]);
        LG[(((size_t)(hbase + h)) * kNS + i) * kNS + (j1 + 1)] = lgt;
      }
    }
  } else {
    // ---------------- CLS row i=0; wave w owns n-tile w ----------------
    const int id = bid - 1600;
    const int jt = id % 7;
    const int b = id / 7;

    const int j1 = jt * 16 + lr;
    const int j1c = j1 > 99 ? 99 : j1;
    const float* Urow = U + ((size_t)(b * kSEQ + j1c)) * kD;
    const float* Qrow = Qm + ((size_t)(b * kSEQ + j1c)) * kD;
    float Xreg[32];
    float gpart = 0.f;
    #pragma unroll
    for (int ks = 0; ks < 4; ++ks) {
      int off = ks * 32 + lg * 8;
      float4 ua = *(const float4*)&Urow[off];
      float4 ub = *(const float4*)&Urow[off + 4];
      float4 qa = *(const float4*)&Qrow[off];
      float4 qb = *(const float4*)&Qrow[off + 4];
      Xreg[ks * 8 + 0] = ua.x + qa.x; Xreg[ks * 8 + 1] = ua.y + qa.y;
      Xreg[ks * 8 + 2] = ua.z + qa.z; Xreg[ks * 8 + 3] = ua.w + qa.w;
      Xreg[ks * 8 + 4] = ub.x + qb.x; Xreg[ks * 8 + 5] = ub.y + qb.y;
      Xreg[ks * 8 + 6] = ub.z + qb.z; Xreg[ks * 8 + 7] = ub.w + qb.w;
      gpart = __builtin_fmaf(ua.x, qa.x, gpart);
      gpart = __builtin_fmaf(ua.y, qa.y, gpart);
      gpart = __builtin_fmaf(ua.z, qa.z, gpart);
      gpart = __builtin_fmaf(ua.w, qa.w, gpart);
      gpart = __builtin_fmaf(ub.x, qb.x, gpart);
      gpart = __builtin_fmaf(ub.y, qb.y, gpart);
      gpart = __builtin_fmaf(ub.z, qb.z, gpart);
      gpart = __builtin_fmaf(ub.w, qb.w, gpart);
    }
    gpart += __shfl_xor(gpart, 16);
    gpart += __shfl_xor(gpart, 32);
    float amul, aadd;
    {
      float mean = (su_[b * kSEQ + j1c] + sw_[b * kSEQ + j1c]) * (1.f / 128.f);
      float ex2 = (nu_[b * kSEQ + j1c] + nw_[b * kSEQ + j1c] + 2.f * gpart) * (1.f / 128.f);
      float var = ex2 - mean * mean;
      float rstd = rsqrtf(var + 1e-5f);
      amul = rstd; aadd = -mean * rstd;
    }
    __syncthreads();

    bf16x8 Af[4];
    #pragma unroll
    for (int ks = 0; ks < 4; ++ks) {
      float ys[8], gg[8], bb[8];
      const int off = ks * 32 + lg * 8;
      *(float4*)&gg[0] = *(const float4*)&gsh[off];
      *(float4*)&gg[4] = *(const float4*)&gsh[off + 4];
      *(float4*)&bb[0] = *(const float4*)&bsh[off];
      *(float4*)&bb[4] = *(const float4*)&bsh[off + 4];
      #pragma unroll
      for (int ee = 0; ee < 8; ++ee) {
        float t = __builtin_fmaf(Xreg[ks * 8 + ee], amul, aadd);
        ys[ee] = fmaxf(__builtin_fmaf(t, gg[ee], bb[ee]), 0.f);
      }
      Af[ks] = pack8(ys);
    }

    const float waE = Wa[32 + lr];
    {
      const int nt = w;  // wave w owns n-tile w
      const int brow = nt * 16 + lr;
      f32x4 acc = {0.f, 0.f, 0.f, 0.f};
      #pragma unroll
      for (int ks = 0; ks < 4; ++ks) {
        int g8 = (ks * 4 + lg) ^ (brow & 15);
        bf16x8 Bf = *(const bf16x8*)&W2sh[brow * 128 + g8 * 8];
        acc = __builtin_amdgcn_mfma_f32_16x16x32_bf16(Af[ks], Bf, acc, 0, 0, 0);
      }
      const float b2v = b2sh[nt * 16 + lr];
      #pragma unroll
      for (int r = 0; r < 4; ++r) {
        float y = acc[r] + b2v;
        float c = leaky(y) * waE;
        c += __shfl_xor(c, 1);
        c += __shfl_xor(c, 2);
        c += __shfl_xor(c, 4);
        c += __shfl_xor(c, 8);
        if (lr == 0) SEsh0[4 * lg + r][nt] = c;
      }
    }
    __syncthreads();
    if (tid < 128) {
      int rowloc = tid & 15, h = tid >> 4;
      int j1o = jt * 16 + rowloc;
      if (j1o <= 99) {
        const int skbase = (b * kH + h) * kNS;
        float lgt = SEsh0[rowloc][h] + sq[skbase] + sk[skbase + j1o + 1] + ba[0];
        LG[(((size_t)(b * kH + h)) * kNS) * kNS + (j1o + 1)] = lgt;
      }
    }
  }
}

// ---------------------------------------------------------------------------
// K2b: softmax + ctx over precomputed logits (in attn region, overwritten).
// grid (H, B, 4 quarters), 512 thr (8 waves; each wave ~3 i-rows).
// ---------------------------------------------------------------------------
__global__ __launch_bounds__(512) void k_sm(
    const float* __restrict__ v,
    float* __restrict__ basis, float* __restrict__ attn) {
  const int h = blockIdx.x;
  const int b = blockIdx.y;
  const int quarter = blockIdx.z;
  const int tid = threadIdx.x;
  const int lane = tid & 63, w = tid >> 6;

  __shared__ float vsh[101][17];
  __shared__ float scr[8][104];

  for (int j = tid >> 4; j < kNS; j += 32)
    vsh[j][tid & 15] = v[((size_t)(b * kNS + j)) * kD + h * 16 + (tid & 15)];
  __syncthreads();

  const int istart = quarter * 26;
  const int iend = istart + 26 < kNS ? istart + 26 : kNS;
  for (int i = istart + w; i < iend; i += 8) {
    float* arow = attn + (((size_t)(b * kH + h)) * kNS + i) * kNS;
    const int j1 = lane + 1;
    const int j2 = lane + 65;
    const bool val1 = (j1 != i);
    const bool val2 = (j2 <= 100) && (j2 != i);
    float l1 = val1 ? arow[j1] : -1e30f;
    float l2 = val2 ? arow[j2] : -1e30f;
    float mx = fmaxf(l1, l2);
    #pragma unroll
    for (int m = 1; m < 64; m <<= 1) mx = fmaxf(mx, __shfl_xor(mx, m));
    float e1 = __expf(l1 - mx);
    float e2 = __expf(l2 - mx);
    float sm = e1 + e2;
    #pragma unroll
    for (int m = 1; m < 64; m <<= 1) sm += __shfl_xor(sm, m);
    float inv = 1.f / sm;
    float a1 = e1 * inv, a2 = e2 * inv;
    arow[j1] = a1;
    scr[w][j1] = a1;
    if (lane < 36) {
      arow[j2] = a2;
      scr[w][j2] = a2;
    }
    if (lane == 0) arow[0] = 0.f;

    const int g = lane >> 4, t = lane & 15;
    float accc = 0.f;
    #pragma unroll 5
    for (int jj = 0; jj < 25; ++jj) {
      int j = 1 + g + jj * 4;
      accc += scr[w][j] * vsh[j][t];
    }
    accc += __shfl_xor(accc, 16);
    accc += __shfl_xor(accc, 32);
    if (lane < 16) basis[(((size_t)(b * kNS + i)) * kH + h) * 16 + t] = accc;
  }
}

}  // namespace

extern "C" void kernel_launch(void* const* d_in, const int* in_sizes, int n_in,
                              void* d_out, int out_size, void* d_ws,
                              size_t ws_size, hipStream_t stream) {
  const float* desc = (const float*)d_in[0];
  const float* nve = (const float*)d_in[1];
  const float* maskM = (const float*)d_in[2];
  const float* Wq = (const float*)d_in[3];
  const float* bq = (const float*)d_in[4];
  const float* Wk = (const float*)d_in[5];
  const float* bk = (const float*)d_in[6];
  const float* Wv = (const float*)d_in[7];
  const float* bv = (const float*)d_in[8];
  const float* W1 = (const float*)d_in[9];
  const float* b1 = (const float*)d_in[10];
  const float* lng = (const float*)d_in[11];
  const float* lnb = (const float*)d_in[12];
  const float* W2 = (const float*)d_in[13];
  const float* b2 = (const float*)d_in[14];
  const float* Wa = (const float*)d_in[15];
  const float* ba = (const float*)d_in[16];

  float* wsf = (float*)d_ws;
  float* U = wsf;                          // 16*100*128
  float* Qm = U + kB * kSEQ * kD;          // 16*100*128
  float* vw = Qm + kB * kSEQ * kD;         // 16*101*128
  float* sqw = vw + kB * kNS * kD;         // 16*8*101
  float* skw = sqw + kB * kH * kNS;
  float* su_ = skw + kB * kH * kNS;        // 16*100 x4
  float* nu_ = su_ + kB * kSEQ;
  float* sw_ = nu_ + kB * kSEQ;
  float* nw_ = sw_ + kB * kSEQ;
  unsigned short* W2bf = (unsigned short*)(nw_ + kB * kSEQ);  // 128*128
  // total ws: ~2.6 MB

  float* basis = (float*)d_out;                       // [B, NS, H, HD]
  float* attn = basis + (size_t)kB * kNS * kH * 16;   // [B, H, NS, NS]
  float* LG = attn;  // logits staged in attn region, overwritten by k_sm

  k_front<<<dim3(480), 256, 0, stream>>>(nve, Wq, bq, Wk, bk, Wv, bv, Wa,
                                         desc, W1, b1, W2,
                                         vw, sqw, skw, U, Qm,
                                         su_, nu_, sw_, nw_, W2bf);
  k_mid<<<dim3(1712), 512, 0, stream>>>(U, Qm, su_, nu_, sw_, nw_, W2bf,
                                        lng, lnb, b2, Wa,
                                        sqw, skw, maskM, ba, LG);
  k_sm<<<dim3(kH, kB, 4), 512, 0, stream>>>(vw, basis, attn);
}

// Round 17
// 69.322 us; speedup vs baseline: 1.0902x; 1.0902x over previous
//
#include <hip/hip_runtime.h>
#include <hip/hip_bf16.h>

namespace {

constexpr int kB = 16;
constexpr int kSEQ = 100;
constexpr int kNS = 101;
constexpr int kD = 128;
constexpr int kH = 8;

typedef __attribute__((ext_vector_type(8))) __bf16 bf16x8;
typedef __attribute__((ext_vector_type(4))) float f32x4;

__device__ __forceinline__ unsigned short f2bf(float f) {
  union { float f; unsigned int u; } c;
  c.f = f;
  unsigned int u = c.u;
  u += 0x7FFFu + ((u >> 16) & 1u);
  return (unsigned short)(u >> 16);
}

__device__ __forceinline__ float leaky(float x) {
  return x > 0.f ? x : 0.01f * x;
}

__device__ __forceinline__ bf16x8 pack8(const float* y) {
  bf16x8 r;
  r[0] = (__bf16)y[0]; r[1] = (__bf16)y[1];
  r[2] = (__bf16)y[2]; r[3] = (__bf16)y[3];
  r[4] = (__bf16)y[4]; r[5] = (__bf16)y[5];
  r[6] = (__bf16)y[6]; r[7] = (__bf16)y[7];
  return r;
}

// ---------------------------------------------------------------------------
// K_FRONT: fused {qkv-proj | U/Q-proj+stats | W2->bf16}. grid 480, 256 thr.
// ---------------------------------------------------------------------------
__global__ __launch_bounds__(256) void k_front(
    const float* __restrict__ nve,
    const float* __restrict__ Wq, const float* __restrict__ bq,
    const float* __restrict__ Wk, const float* __restrict__ bk,
    const float* __restrict__ Wv, const float* __restrict__ bv,
    const float* __restrict__ Wa,
    const float* __restrict__ desc, const float* __restrict__ W1,
    const float* __restrict__ b1, const float* __restrict__ W2,
    float* __restrict__ v, float* __restrict__ sq, float* __restrict__ sk,
    float* __restrict__ U, float* __restrict__ Qm,
    float* __restrict__ su_, float* __restrict__ nu_,
    float* __restrict__ sw_, float* __restrict__ nw_,
    unsigned short* __restrict__ W2bf) {
  __shared__ float X[8][128];
  __shared__ float part[4][4][4];
  const int bid = blockIdx.x;
  const int tid = threadIdx.x;

  if (bid < 208) {
    const int b = bid / 13;
    const int n0 = (bid % 13) * 8;
    const int d = tid & 127, rh = tid >> 7;
    {
      int r = tid >> 5, c = (tid & 31) * 4;
      int n = n0 + r; if (n > 100) n = 100;
      *(float4*)&X[r][c] = *(const float4*)&nve[((size_t)(b * kNS + n)) * kD + c];
    }
    __syncthreads();

    float aq[4], ak[4], av[4];
    const float bqv = bq[d], bkv = bk[d], bvv = bv[d];
    #pragma unroll
    for (int r = 0; r < 4; ++r) { aq[r] = bqv; ak[r] = bkv; av[r] = bvv; }

    const float* wqr = Wq + (size_t)d * kD;
    const float* wkr = Wk + (size_t)d * kD;
    const float* wvr = Wv + (size_t)d * kD;
    for (int kk = 0; kk < kD; ++kk) {
      float wq = wqr[kk], wk = wkr[kk], wv = wvr[kk];
      #pragma unroll
      for (int r = 0; r < 4; ++r) {
        float x = X[rh * 4 + r][kk];
        aq[r] += wq * x;
        ak[r] += wk * x;
        av[r] += wv * x;
      }
    }

    const int t = d & 15, h = d >> 4;
    const float waq = Wa[t], wak = Wa[16 + t];
    #pragma unroll
    for (int r = 0; r < 4; ++r) {
      int n = n0 + rh * 4 + r;
      if (n < kNS) {
        v[((size_t)(b * kNS + n)) * kD + d] = av[r];
        float cq = leaky(aq[r]) * waq;
        float ck = leaky(ak[r]) * wak;
        cq += __shfl_xor(cq, 1); ck += __shfl_xor(ck, 1);
        cq += __shfl_xor(cq, 2); ck += __shfl_xor(ck, 2);
        cq += __shfl_xor(cq, 4); ck += __shfl_xor(ck, 4);
        cq += __shfl_xor(cq, 8); ck += __shfl_xor(ck, 8);
        if (t == 0) {
          sq[(b * kH + h) * kNS + n] = cq;
          sk[(b * kH + h) * kNS + n] = ck;
        }
      }
    }
  } else if (bid < 416) {
    const int id = bid - 208;
    const int b = id / 13;
    const int s0 = (id % 13) * 8;
    const int d = tid & 127, rh = tid >> 7;
    const int lane = tid & 63, wv = tid >> 6;
    {
      int r = tid >> 5, c = (tid & 31) * 4;
      int s = s0 + r; if (s > 99) s = 99;
      *(float4*)&X[r][c] = *(const float4*)&desc[((size_t)(b * kSEQ + s)) * kD + c];
    }
    __syncthreads();

    float aU[4], aQ[4];
    const float b1v = b1[d];
    #pragma unroll
    for (int r = 0; r < 4; ++r) { aU[r] = b1v; aQ[r] = 0.f; }

    const float* w1r = W1 + (size_t)d * (2 * kD);
    for (int kk = 0; kk < kD; ++kk) {
      float wa = w1r[kk], wb = w1r[kD + kk];
      #pragma unroll
      for (int r = 0; r < 4; ++r) {
        float x = X[rh * 4 + r][kk];
        aU[r] += wa * x;
        aQ[r] += wb * x;
      }
    }
    #pragma unroll
    for (int r = 0; r < 4; ++r) {
      int s = s0 + rh * 4 + r;
      if (s < kSEQ) {
        size_t base = ((size_t)(b * kSEQ + s)) * kD + d;
        U[base] = aU[r];
        Qm[base] = aQ[r];
      }
    }
    #pragma unroll
    for (int r = 0; r < 4; ++r) {
      float s1 = aU[r], s2 = aU[r] * aU[r], s3 = aQ[r], s4 = aQ[r] * aQ[r];
      #pragma unroll
      for (int m = 1; m < 64; m <<= 1) {
        s1 += __shfl_xor(s1, m);
        s2 += __shfl_xor(s2, m);
        s3 += __shfl_xor(s3, m);
        s4 += __shfl_xor(s4, m);
      }
      if (lane == 0) {
        part[wv][r][0] = s1; part[wv][r][1] = s2;
        part[wv][r][2] = s3; part[wv][r][3] = s4;
      }
    }
    __syncthreads();
    if (tid < 32) {
      int r = tid & 7, st = tid >> 3;
      int rh2 = r >> 2, rl = r & 3;
      float val = part[rh2 * 2][rl][st] + part[rh2 * 2 + 1][rl][st];
      int s = s0 + r;
      if (s < kSEQ) {
        float* dst = (st == 0) ? su_ : (st == 1) ? nu_ : (st == 2) ? sw_ : nw_;
        dst[b * kSEQ + s] = val;
      }
    }
  } else {
    int idx = (bid - 416) * 256 + tid;
    W2bf[idx] = f2bf(W2[idx]);
  }
}

// ---------------------------------------------------------------------------
// K_MID: fused {SE transposed-GEMM | CLS row}. grid 1712, 512 thr (8 waves).
//   blocks [0,1600): SE, 1 i-row; wave w owns j-tile w (jt 7 predicated off).
//   blocks [1600,1712): CLS; wave w owns n-tile w.
// Gram computed in-block (f32 dot + 2 shuffles). Minimal serial chain.
// ---------------------------------------------------------------------------
__global__ __launch_bounds__(512) void k_mid(
    const float* __restrict__ U, const float* __restrict__ Qm,
    const float* __restrict__ su_, const float* __restrict__ nu_,
    const float* __restrict__ sw_, const float* __restrict__ nw_,
    const unsigned short* __restrict__ W2bf,
    const float* __restrict__ lng, const float* __restrict__ lnb,
    const float* __restrict__ b2, const float* __restrict__ Wa,
    float* __restrict__ SE) {
  const int bid = blockIdx.x;
  const int tid = threadIdx.x;
  const int lane = tid & 63, w = tid >> 6;
  const int lr = lane & 15, lg = lane >> 4;

  __shared__ __align__(16) unsigned short W2sh[128 * 128];  // 32 KB swizzled
  __shared__ __align__(16) float gsh[128], bsh[128], b2sh[128];
  __shared__ float SEsh0[16][8];

  #pragma unroll
  for (int itr = 0; itr < 4; ++itr) {
    uint4 val = ((const uint4*)W2bf)[itr * 512 + tid];
    int f = (itr * 512 + tid) * 8;
    int row = f >> 7, g8 = (f >> 3) & 15;
    *(uint4*)&W2sh[row * 128 + ((g8 ^ (row & 15)) << 3)] = val;
  }
  if (tid < 128) {
    gsh[tid] = lng[tid];
    b2sh[tid] = b2[tid];
  } else if (tid < 256) {
    bsh[tid - 128] = lnb[tid - 128];
  }

  if (bid < 1600) {
    // ---------------- SE, transposed GEMM, 1 i-row, 8-way j ----------------
    const int i0 = bid % 100;
    const int b = bid / 100;

    const float* Urow = U + ((size_t)(b * kSEQ + i0)) * kD;
    float Ureg[32];
    #pragma unroll
    for (int ks = 0; ks < 4; ++ks) {
      int off = ks * 32 + lg * 8;
      *(float4*)&Ureg[ks * 8] = *(const float4*)&Urow[off];
      *(float4*)&Ureg[ks * 8 + 4] = *(const float4*)&Urow[off + 4];
    }
    const float suv = su_[b * kSEQ + i0], nuv = nu_[b * kSEQ + i0];
    float wa4[4];
    *(float4*)wa4 = *(const float4*)&Wa[32 + 4 * lg];

    const int j1 = w * 16 + lr;          // wave w owns j-tile w (0..7)
    const int j1c = j1 > 99 ? 99 : j1;
    const float swv = sw_[b * kSEQ + j1c];
    const float nwv = nw_[b * kSEQ + j1c];
    const float* Qrow = Qm + ((size_t)(b * kSEQ + j1c)) * kD;
    float Qreg[32];
    #pragma unroll
    for (int ks = 0; ks < 4; ++ks) {
      const int off = ks * 32 + lg * 8;
      *(float4*)&Qreg[ks * 8] = *(const float4*)&Qrow[off];
      *(float4*)&Qreg[ks * 8 + 4] = *(const float4*)&Qrow[off + 4];
    }
    float gpart = 0.f;
    #pragma unroll
    for (int e = 0; e < 32; ++e) gpart = __builtin_fmaf(Ureg[e], Qreg[e], gpart);
    gpart += __shfl_xor(gpart, 16);
    gpart += __shfl_xor(gpart, 32);

    const float mean = (suv + swv) * (1.f / 128.f);
    const float ex2 = (nuv + nwv + 2.f * gpart) * (1.f / 128.f);
    const float var = ex2 - mean * mean;
    const float rstd = rsqrtf(var + 1e-5f);
    const float amul = rstd, aadd = -mean * rstd;
    __syncthreads();

    bf16x8 Bf[4];
    #pragma unroll
    for (int ks = 0; ks < 4; ++ks) {
      const int off = ks * 32 + lg * 8;
      float gg[8], bb[8], ys[8];
      *(float4*)&gg[0] = *(const float4*)&gsh[off];
      *(float4*)&gg[4] = *(const float4*)&gsh[off + 4];
      *(float4*)&bb[0] = *(const float4*)&bsh[off];
      *(float4*)&bb[4] = *(const float4*)&bsh[off + 4];
      #pragma unroll
      for (int ee = 0; ee < 8; ++ee) {
        float x = Ureg[ks * 8 + ee] + Qreg[ks * 8 + ee];
        float tt = __builtin_fmaf(x, amul, aadd);
        ys[ee] = fmaxf(__builtin_fmaf(tt, gg[ee], bb[ee]), 0.f);
      }
      Bf[ks] = pack8(ys);
    }

    #pragma unroll
    for (int h = 0; h < 8; ++h) {
      f32x4 acc = *(const f32x4*)&b2sh[h * 16 + 4 * lg];  // C-init = b2
      #pragma unroll
      for (int ks = 0; ks < 4; ++ks) {
        const int row = h * 16 + lr;
        const int g8 = (ks * 4 + lg) ^ lr;
        bf16x8 Af = *(const bf16x8*)&W2sh[row * 128 + g8 * 8];
        acc = __builtin_amdgcn_mfma_f32_16x16x32_bf16(Af, Bf[ks], acc, 0, 0, 0);
      }
      float s = 0.f;
      #pragma unroll
      for (int r = 0; r < 4; ++r) s += leaky(acc[r]) * wa4[r];
      s += __shfl_xor(s, 16);
      s += __shfl_xor(s, 32);
      if (lane < 16 && j1 <= 99)
        SE[(((size_t)(b * kH + h)) * kNS + (i0 + 1)) * kNS + (j1 + 1)] = s;
    }
  } else {
    // ---------------- CLS row i=0; wave w owns n-tile w ----------------
    const int id = bid - 1600;
    const int jt = id % 7;
    const int b = id / 7;

    const int j1 = jt * 16 + lr;
    const int j1c = j1 > 99 ? 99 : j1;
    const float* Urow = U + ((size_t)(b * kSEQ + j1c)) * kD;
    const float* Qrow = Qm + ((size_t)(b * kSEQ + j1c)) * kD;
    float Xreg[32];
    float gpart = 0.f;
    #pragma unroll
    for (int ks = 0; ks < 4; ++ks) {
      int off = ks * 32 + lg * 8;
      float4 ua = *(const float4*)&Urow[off];
      float4 ub = *(const float4*)&Urow[off + 4];
      float4 qa = *(const float4*)&Qrow[off];
      float4 qb = *(const float4*)&Qrow[off + 4];
      Xreg[ks * 8 + 0] = ua.x + qa.x; Xreg[ks * 8 + 1] = ua.y + qa.y;
      Xreg[ks * 8 + 2] = ua.z + qa.z; Xreg[ks * 8 + 3] = ua.w + qa.w;
      Xreg[ks * 8 + 4] = ub.x + qb.x; Xreg[ks * 8 + 5] = ub.y + qb.y;
      Xreg[ks * 8 + 6] = ub.z + qb.z; Xreg[ks * 8 + 7] = ub.w + qb.w;
      gpart = __builtin_fmaf(ua.x, qa.x, gpart);
      gpart = __builtin_fmaf(ua.y, qa.y, gpart);
      gpart = __builtin_fmaf(ua.z, qa.z, gpart);
      gpart = __builtin_fmaf(ua.w, qa.w, gpart);
      gpart = __builtin_fmaf(ub.x, qb.x, gpart);
      gpart = __builtin_fmaf(ub.y, qb.y, gpart);
      gpart = __builtin_fmaf(ub.z, qb.z, gpart);
      gpart = __builtin_fmaf(ub.w, qb.w, gpart);
    }
    gpart += __shfl_xor(gpart, 16);
    gpart += __shfl_xor(gpart, 32);
    float amul, aadd;
    {
      float mean = (su_[b * kSEQ + j1c] + sw_[b * kSEQ + j1c]) * (1.f / 128.f);
      float ex2 = (nu_[b * kSEQ + j1c] + nw_[b * kSEQ + j1c] + 2.f * gpart) * (1.f / 128.f);
      float var = ex2 - mean * mean;
      float rstd = rsqrtf(var + 1e-5f);
      amul = rstd; aadd = -mean * rstd;
    }
    __syncthreads();

    bf16x8 Af[4];
    #pragma unroll
    for (int ks = 0; ks < 4; ++ks) {
      float ys[8], gg[8], bb[8];
      const int off = ks * 32 + lg * 8;
      *(float4*)&gg[0] = *(const float4*)&gsh[off];
      *(float4*)&gg[4] = *(const float4*)&gsh[off + 4];
      *(float4*)&bb[0] = *(const float4*)&bsh[off];
      *(float4*)&bb[4] = *(const float4*)&bsh[off + 4];
      #pragma unroll
      for (int ee = 0; ee < 8; ++ee) {
        float t = __builtin_fmaf(Xreg[ks * 8 + ee], amul, aadd);
        ys[ee] = fmaxf(__builtin_fmaf(t, gg[ee], bb[ee]), 0.f);
      }
      Af[ks] = pack8(ys);
    }

    const float waE = Wa[32 + lr];
    {
      const int nt = w;  // wave w owns n-tile w
      const int brow = nt * 16 + lr;
      f32x4 acc = {0.f, 0.f, 0.f, 0.f};
      #pragma unroll
      for (int ks = 0; ks < 4; ++ks) {
        int g8 = (ks * 4 + lg) ^ (brow & 15);
        bf16x8 Bf = *(const bf16x8*)&W2sh[brow * 128 + g8 * 8];
        acc = __builtin_amdgcn_mfma_f32_16x16x32_bf16(Af[ks], Bf, acc, 0, 0, 0);
      }
      const float b2v = b2sh[nt * 16 + lr];
      #pragma unroll
      for (int r = 0; r < 4; ++r) {
        float y = acc[r] + b2v;
        float c = leaky(y) * waE;
        c += __shfl_xor(c, 1);
        c += __shfl_xor(c, 2);
        c += __shfl_xor(c, 4);
        c += __shfl_xor(c, 8);
        if (lr == 0) SEsh0[4 * lg + r][nt] = c;
      }
    }
    __syncthreads();
    if (tid < 128) {
      int rowloc = tid & 15, h = tid >> 4;
      int j1o = jt * 16 + rowloc;
      if (j1o <= 99)
        SE[(((size_t)(b * kH + h)) * kNS) * kNS + (j1o + 1)] = SEsh0[rowloc][h];
    }
  }
}

// ---------------------------------------------------------------------------
// K2b: softmax + ctx. SE read from attn region (then overwritten with attn).
// grid (H, B, 4 quarters), 512 thr (8 waves; each wave ~3 i-rows).
// ---------------------------------------------------------------------------
__global__ __launch_bounds__(512) void k_sm(
    const float* __restrict__ sq, const float* __restrict__ sk,
    const float* __restrict__ v, const float* __restrict__ maskM,
    const float* __restrict__ ba,
    float* __restrict__ basis, float* __restrict__ attn) {
  const int h = blockIdx.x;
  const int b = blockIdx.y;
  const int quarter = blockIdx.z;
  const int tid = threadIdx.x;
  const int lane = tid & 63, w = tid >> 6;

  __shared__ float vsh[101][17];
  __shared__ float scr[8][104];

  for (int j = tid >> 4; j < kNS; j += 32)
    vsh[j][tid & 15] = v[((size_t)(b * kNS + j)) * kD + h * 16 + (tid & 15)];
  __syncthreads();

  const float bav = ba[0];
  const int skbase = (b * kH + h) * kNS;
  const int istart = quarter * 26;
  const int iend = istart + 26 < kNS ? istart + 26 : kNS;
  for (int i = istart + w; i < iend; i += 8) {
    const float sqv = sq[skbase + i];
    float* arow = attn + (((size_t)(b * kH + h)) * kNS + i) * kNS;
    const int j1 = lane + 1;
    const int j2 = lane + 65;
    const bool val1 = (j1 != i);
    const bool val2 = (j2 <= 100) && (j2 != i);
    float l1 = -1e30f, l2 = -1e30f;
    {
      float lgt = sqv + sk[skbase + j1] + arow[j1] + bav;
      if (i >= 1) {
        float p = maskM[(((size_t)(b * kH + h)) * kSEQ + (i - 1)) * kSEQ + (j1 - 1)];
        p = fminf(fmaxf(p, 1e-6f), 1.f - 1e-6f);
        lgt += __logf(__fdividef(p, 1.f - p));
      }
      if (val1) l1 = lgt;
    }
    if (val2) {
      float lgt = sqv + sk[skbase + j2] + arow[j2] + bav;
      if (i >= 1) {
        float p = maskM[(((size_t)(b * kH + h)) * kSEQ + (i - 1)) * kSEQ + (j2 - 1)];
        p = fminf(fmaxf(p, 1e-6f), 1.f - 1e-6f);
        lgt += __logf(__fdividef(p, 1.f - p));
      }
      l2 = lgt;
    }
    float mx = fmaxf(l1, l2);
    #pragma unroll
    for (int m = 1; m < 64; m <<= 1) mx = fmaxf(mx, __shfl_xor(mx, m));
    float e1 = __expf(l1 - mx);
    float e2 = __expf(l2 - mx);
    float sm = e1 + e2;
    #pragma unroll
    for (int m = 1; m < 64; m <<= 1) sm += __shfl_xor(sm, m);
    float inv = 1.f / sm;
    float a1 = e1 * inv, a2 = e2 * inv;
    arow[j1] = a1;
    scr[w][j1] = a1;
    if (lane < 36) {
      arow[j2] = a2;
      scr[w][j2] = a2;
    }
    if (lane == 0) arow[0] = 0.f;

    const int g = lane >> 4, t = lane & 15;
    float accc = 0.f;
    #pragma unroll 5
    for (int jj = 0; jj < 25; ++jj) {
      int j = 1 + g + jj * 4;
      accc += scr[w][j] * vsh[j][t];
    }
    accc += __shfl_xor(accc, 16);
    accc += __shfl_xor(accc, 32);
    if (lane < 16) basis[(((size_t)(b * kNS + i)) * kH + h) * 16 + t] = accc;
  }
}

}  // namespace

extern "C" void kernel_launch(void* const* d_in, const int* in_sizes, int n_in,
                              void* d_out, int out_size, void* d_ws,
                              size_t ws_size, hipStream_t stream) {
  const float* desc = (const float*)d_in[0];
  const float* nve = (const float*)d_in[1];
  const float* maskM = (const float*)d_in[2];
  const float* Wq = (const float*)d_in[3];
  const float* bq = (const float*)d_in[4];
  const float* Wk = (const float*)d_in[5];
  const float* bk = (const float*)d_in[6];
  const float* Wv = (const float*)d_in[7];
  const float* bv = (const float*)d_in[8];
  const float* W1 = (const float*)d_in[9];
  const float* b1 = (const float*)d_in[10];
  const float* lng = (const float*)d_in[11];
  const float* lnb = (const float*)d_in[12];
  const float* W2 = (const float*)d_in[13];
  const float* b2 = (const float*)d_in[14];
  const float* Wa = (const float*)d_in[15];
  const float* ba = (const float*)d_in[16];

  float* wsf = (float*)d_ws;
  float* U = wsf;                          // 16*100*128
  float* Qm = U + kB * kSEQ * kD;          // 16*100*128
  float* vw = Qm + kB * kSEQ * kD;         // 16*101*128
  float* sqw = vw + kB * kNS * kD;         // 16*8*101
  float* skw = sqw + kB * kH * kNS;
  float* su_ = skw + kB * kH * kNS;        // 16*100 x4
  float* nu_ = su_ + kB * kSEQ;
  float* sw_ = nu_ + kB * kSEQ;
  float* nw_ = sw_ + kB * kSEQ;
  unsigned short* W2bf = (unsigned short*)(nw_ + kB * kSEQ);  // 128*128
  // total ws: ~2.6 MB

  float* basis = (float*)d_out;                       // [B, NS, H, HD]
  float* attn = basis + (size_t)kB * kNS * kH * 16;   // [B, H, NS, NS]
  float* SE = attn;  // SE staged in attn region, overwritten by k_sm

  k_front<<<dim3(480), 256, 0, stream>>>(nve, Wq, bq, Wk, bk, Wv, bv, Wa,
                                         desc, W1, b1, W2,
                                         vw, sqw, skw, U, Qm,
                                         su_, nu_, sw_, nw_, W2bf);
  k_mid<<<dim3(1712), 512, 0, stream>>>(U, Qm, su_, nu_, sw_, nw_, W2bf,
                                        lng, lnb, b2, Wa, SE);
  k_sm<<<dim3(kH, kB, 4), 512, 0, stream>>>(sqw, skw, vw, maskM, ba,
                                            basis, attn);
}